// Round 6
// baseline (3032.765 us; speedup 1.0000x reference)
//
#include <hip/hip_runtime.h>
#include <hip/hip_bf16.h>

// ---------------------------------------------------------------------------
// Model: self/ally tanh-Linear encoders -> segment mean -> cat MLP ->
//        8192-step LSTM (H=20) -> policy/value heads.
//   k_bounds  : segment start offsets via binary search
//   k_segmean : 1 wave/segment; coalesced 64-row LDS tiles; W via scalar loads
//   k_feats   : 256-thr blocks; xg written float4 (bias included)
//   k_lstm    : 4-wave pipelined ring (wave w owns steps t%4==w); h,c handed
//               through LDS slots, seqlock with EXPLICIT threadfence_block
//               fences + lane-0 seq store. Per-step math = R4's exact
//               (passed at 1.2e-4): sigmoid/tanh via __expf, unscaled cell.
//   k_heads   : 256-thr blocks, float4 loads/stores
// ---------------------------------------------------------------------------

#define T_STEPS 8192
#define TOTAL_ROWS 1048576
#define DSELF 128
#define DALLY 64
#define HS 20
#define NOUT 16

__device__ __forceinline__ float rcp_f(float x) { return __builtin_amdgcn_rcpf(x); }
__device__ __forceinline__ float sigm_f(float x) { return rcp_f(1.0f + __expf(-x)); }
// tanh(x) = 2*sigmoid(2x) - 1 ; saturates correctly at +-inf
__device__ __forceinline__ float tanh_f(float x) { return fmaf(2.0f, sigm_f(2.0f * x), -1.0f); }

// --------------------------- K1: segment boundaries -------------------------
__global__ void k_bounds(const int* __restrict__ seg, int* __restrict__ start) {
  int s = blockIdx.x * blockDim.x + threadIdx.x;
  if (s > T_STEPS) return;
  if (s == T_STEPS) { start[s] = TOTAL_ROWS; return; }
  int lo = 0, hi = TOTAL_ROWS;
  while (lo < hi) {
    int mid = (lo + hi) >> 1;
    if (seg[mid] < s) lo = mid + 1; else hi = mid;
  }
  start[s] = lo;
}

// ------------------- K2: fused ally tanh-linear + segment mean --------------
// one wave per segment. Rows staged through LDS in 64-row tiles so global
// loads are fully coalesced (wave reads 1KB contiguous per instruction).
__global__ __launch_bounds__(64) void k_segmean(
    const float* __restrict__ ally, const int* __restrict__ start,
    const float* __restrict__ W_ally, const float* __restrict__ b_ally,
    float* __restrict__ avg) {
  __shared__ float tile[64][DALLY + 2];
  __shared__ float red[64][HS + 1];
  const int lane = threadIdx.x;
  const int s = blockIdx.x;
  const int r0 = start[s], r1 = start[s + 1];
  float acc[HS];
#pragma unroll
  for (int h = 0; h < HS; ++h) acc[h] = 0.0f;
  for (int base = r0; base < r1; base += 64) {
    const int m = min(64, r1 - base);
    __syncthreads();  // protect tile from previous iteration's readers
    for (int idx = lane; idx < m * 16; idx += 64) {
      const int rr = idx >> 4, cc = (idx & 15) << 2;
      const float4 v = *reinterpret_cast<const float4*>(
          ally + (size_t)(base + rr) * DALLY + cc);
      *reinterpret_cast<float2*>(&tile[rr][cc])     = make_float2(v.x, v.y);
      *reinterpret_cast<float2*>(&tile[rr][cc + 2]) = make_float2(v.z, v.w);
    }
    __syncthreads();
    if (lane < m) {
      float dot[HS];
#pragma unroll
      for (int h = 0; h < HS; ++h) dot[h] = b_ally[h];  // uniform -> SGPR
#pragma unroll
      for (int j = 0; j < DALLY; j += 4) {
        const float2 xa = *reinterpret_cast<const float2*>(&tile[lane][j]);
        const float2 xb = *reinterpret_cast<const float2*>(&tile[lane][j + 2]);
#pragma unroll
        for (int h = 0; h < HS; ++h) {
          const float4 w = *reinterpret_cast<const float4*>(&W_ally[h * DALLY + j]);
          dot[h] = fmaf(xa.x, w.x, dot[h]);
          dot[h] = fmaf(xa.y, w.y, dot[h]);
          dot[h] = fmaf(xb.x, w.z, dot[h]);
          dot[h] = fmaf(xb.y, w.w, dot[h]);
        }
      }
#pragma unroll
      for (int h = 0; h < HS; ++h) acc[h] += tanh_f(dot[h]);
    }
  }
#pragma unroll
  for (int h = 0; h < HS; ++h) red[lane][h] = acc[h];
  __syncthreads();
  if (lane < HS) {
    float t = 0.0f;
    for (int l = 0; l < 64; ++l) t += red[l][lane];
    avg[(size_t)s * HS + lane] = t / (float)(r1 - r0);
  }
}

// ------------- K3: per-timestep features: s, cat, xg, value head ------------
__global__ __launch_bounds__(256) void k_feats(
    const float* __restrict__ self_in, const float* __restrict__ avg,
    const float* __restrict__ W_self, const float* __restrict__ b_self,
    const float* __restrict__ W_cat, const float* __restrict__ b_cat,
    const float* __restrict__ W_ih, const float* __restrict__ b_ih,
    const float* __restrict__ b_hh,
    const float* __restrict__ W_vfc, const float* __restrict__ b_vfc,
    const float* __restrict__ W_v, const float* __restrict__ b_v,
    float* __restrict__ xg, float* __restrict__ v_out) {
  __shared__ float s_ws[HS * DSELF];
  __shared__ float s_bs[HS];
  __shared__ float s_wc[HS * 2 * HS];
  __shared__ float s_bc[HS];
  __shared__ float s_wih[4 * HS * HS];
  __shared__ float s_bih[4 * HS];
  __shared__ float s_wv[HS * HS];
  __shared__ float s_bv[HS];
  __shared__ float s_wvv[HS];
  __shared__ float s_bvs;
  const int tid = threadIdx.x;
  for (int i = tid; i < HS * DSELF; i += 256) s_ws[i] = W_self[i];
  for (int i = tid; i < HS * 2 * HS; i += 256) s_wc[i] = W_cat[i];
  for (int i = tid; i < 4 * HS * HS; i += 256) s_wih[i] = W_ih[i];
  for (int i = tid; i < HS * HS; i += 256) s_wv[i] = W_vfc[i];
  if (tid < HS) {
    s_bs[tid] = b_self[tid]; s_bc[tid] = b_cat[tid];
    s_bv[tid] = b_vfc[tid];  s_wvv[tid] = W_v[tid];
  }
  if (tid < 4 * HS) s_bih[tid] = b_ih[tid] + b_hh[tid];
  if (tid == 0) s_bvs = b_v[0];
  __syncthreads();

  const int t = blockIdx.x * 256 + tid;
  const float* srow = self_in + (size_t)t * DSELF;
  float acc[HS];
#pragma unroll
  for (int h = 0; h < HS; ++h) acc[h] = s_bs[h];
  for (int j = 0; j < DSELF / 4; ++j) {
    const float4 x = *reinterpret_cast<const float4*>(srow + j * 4);
#pragma unroll
    for (int h = 0; h < HS; ++h) {
      const float4 w = *reinterpret_cast<const float4*>(&s_ws[h * DSELF + j * 4]);
      acc[h] = fmaf(x.x, w.x, acc[h]);
      acc[h] = fmaf(x.y, w.y, acc[h]);
      acc[h] = fmaf(x.z, w.z, acc[h]);
      acc[h] = fmaf(x.w, w.w, acc[h]);
    }
  }
  float sv[HS], av[HS];
#pragma unroll
  for (int h = 0; h < HS; ++h) sv[h] = tanh_f(acc[h]);
  {
    const float4* ap = reinterpret_cast<const float4*>(avg + (size_t)t * HS);
#pragma unroll
    for (int q = 0; q < HS / 4; ++q) {
      const float4 a4 = ap[q];
      av[q * 4 + 0] = a4.x; av[q * 4 + 1] = a4.y;
      av[q * 4 + 2] = a4.z; av[q * 4 + 3] = a4.w;
    }
  }
  float cat[HS];
#pragma unroll
  for (int h = 0; h < HS; ++h) {
    float a = s_bc[h];
#pragma unroll
    for (int j = 0; j < HS; ++j) a = fmaf(sv[j], s_wc[h * 2 * HS + j], a);
#pragma unroll
    for (int j = 0; j < HS; ++j) a = fmaf(av[j], s_wc[h * 2 * HS + HS + j], a);
    cat[h] = tanh_f(a);
  }
  // xg written as float4 groups of gate rows (i,f,g,o row-major order 0..79)
#pragma unroll 2
  for (int jj = 0; jj < 4 * HS; jj += 4) {
    float a0 = s_bih[jj], a1 = s_bih[jj + 1], a2 = s_bih[jj + 2], a3 = s_bih[jj + 3];
#pragma unroll
    for (int k = 0; k < HS; ++k) {
      const float cv = cat[k];
      a0 = fmaf(cv, s_wih[(jj + 0) * HS + k], a0);
      a1 = fmaf(cv, s_wih[(jj + 1) * HS + k], a1);
      a2 = fmaf(cv, s_wih[(jj + 2) * HS + k], a2);
      a3 = fmaf(cv, s_wih[(jj + 3) * HS + k], a3);
    }
    float4 o4; o4.x = a0; o4.y = a1; o4.z = a2; o4.w = a3;
    *reinterpret_cast<float4*>(&xg[(size_t)t * 80 + jj]) = o4;
  }
  float vacc = s_bvs;
#pragma unroll
  for (int h = 0; h < HS; ++h) {
    float a = s_bv[h];
#pragma unroll
    for (int k = 0; k < HS; ++k) a = fmaf(cat[k], s_wv[h * HS + k], a);
    vacc = fmaf(tanh_f(a), s_wvv[h], vacc);
  }
  v_out[t] = vacc;
}

// ----------------------------- K4: LSTM scan --------------------------------
// 4 waves, wave w owns steps t%4==w. Per step: spin (relaxed) on seq[(t-1)&7],
// acquire fence, read h/c from LDS slot, compute R4-exact gate math
// (i|f pass1 on lanes 0-19|32-51, g|o pass2; f,o via permlane32_swap),
// write h,c to slot t&7, release fence, lane-0 seq store.
__global__ __launch_bounds__(256) void k_lstm(
    const float* __restrict__ xg, const float* __restrict__ Whh,
    const float* __restrict__ h0, const float* __restrict__ c0,
    float* __restrict__ hout) {
  __shared__ float lds_h[8][32];
  __shared__ float lds_c[8][32];
  __shared__ int lds_seq[8];
  const int tid = threadIdx.x;
  const int wv = tid >> 6;
  const int lane = tid & 63;
  const int kk = lane & 31;
  const int kc = kk < HS ? kk : HS - 1;            // clamp dup lanes
  const int r1 = kc + ((lane >= 32) ? HS : 0);     // i rows | f rows
  const int r2 = r1 + 2 * HS;                      // g rows | o rows

  // pass2 nonlinearity: tanh (g) on lanes<32, sigmoid (o) on lanes>=32
  const float S = (lane < 32) ? 2.0f : 1.0f;
  const float A = (lane < 32) ? 2.0f : 1.0f;
  const float B = (lane < 32) ? -1.0f : 0.0f;

  float wa[HS], wb[HS];
#pragma unroll
  for (int j = 0; j < HS; ++j) {
    wa[j] = Whh[r1 * HS + j];
    wb[j] = Whh[r2 * HS + j];
  }

  if (tid < 8) lds_seq[tid] = -999;
  __syncthreads();
  if (wv == 0) {
    if (lane < HS) {
      lds_h[7][lane] = h0[lane];
      lds_c[7][lane] = c0[lane];
    }
    __threadfence_block();                          // release
    if (lane == 0)
      __hip_atomic_store(&lds_seq[7], -1, __ATOMIC_RELAXED,
                         __HIP_MEMORY_SCOPE_WORKGROUP);
  }

  int t = wv;
  const float* px1 = xg + (size_t)t * 80 + r1;
  const float* px2 = xg + (size_t)t * 80 + r2;
  // 2-deep per-wave prefetch = 8 global steps of slack. Tail reads spill
  // <=2560B past xg into hbuf (valid memory, values never consumed).
  float x10 = px1[0],   x20 = px2[0];
  float x11 = px1[320], x21 = px2[320];

  for (int n = 0; n < T_STEPS / 4; ++n) {
    const int rs = (t - 1) & 7;
    while (__hip_atomic_load(&lds_seq[rs], __ATOMIC_RELAXED,
                             __HIP_MEMORY_SCOPE_WORKGROUP) != t - 1) {}
    __threadfence_block();                          // acquire
    const float4* hsp = reinterpret_cast<const float4*>(&lds_h[rs][0]);
    const float4 hq0 = hsp[0], hq1 = hsp[1], hq2 = hsp[2], hq3 = hsp[3],
                 hq4 = hsp[4];
    const float csp = lds_c[rs][kc];
    float hv[HS];
    hv[0] = hq0.x;  hv[1] = hq0.y;  hv[2] = hq0.z;  hv[3] = hq0.w;
    hv[4] = hq1.x;  hv[5] = hq1.y;  hv[6] = hq1.z;  hv[7] = hq1.w;
    hv[8] = hq2.x;  hv[9] = hq2.y;  hv[10] = hq2.z; hv[11] = hq2.w;
    hv[12] = hq3.x; hv[13] = hq3.y; hv[14] = hq3.z; hv[15] = hq3.w;
    hv[16] = hq4.x; hv[17] = hq4.y; hv[18] = hq4.z; hv[19] = hq4.w;

    float p0 = 0.f, p1 = 0.f, p2 = 0.f, p3 = 0.f;
    float q0 = 0.f, q1 = 0.f, q2 = 0.f, q3 = 0.f;
#pragma unroll
    for (int j = 0; j < HS; j += 4) {
      p0 = fmaf(wa[j],     hv[j],     p0); q0 = fmaf(wb[j],     hv[j],     q0);
      p1 = fmaf(wa[j + 1], hv[j + 1], p1); q1 = fmaf(wb[j + 1], hv[j + 1], q1);
      p2 = fmaf(wa[j + 2], hv[j + 2], p2); q2 = fmaf(wb[j + 2], hv[j + 2], q2);
      p3 = fmaf(wa[j + 3], hv[j + 3], p3); q3 = fmaf(wb[j + 3], hv[j + 3], q3);
    }
    const float a1 = x10 + ((p0 + p1) + (p2 + p3));
    const float a2 = x20 + ((q0 + q1) + (q2 + q3));
    // rotate prefetch (off critical path)
    x10 = x11; x20 = x21;
    px1 += 320; px2 += 320;
    x11 = px1[320]; x21 = px2[320];

    const float t1 = rcp_f(1.0f + __expf(-a1));                 // i | f
    const float t2 = fmaf(A, rcp_f(1.0f + __expf(-S * a2)), B); // g | o
    auto rfp = __builtin_amdgcn_permlane32_swap(
        __float_as_uint(t1), __float_as_uint(t1), false, false);
    auto rop = __builtin_amdgcn_permlane32_swap(
        __float_as_uint(t2), __float_as_uint(t2), false, false);
    const float fp = __uint_as_float(rfp[1]);   // lane k: f_k
    const float op = __uint_as_float(rop[1]);   // lane k: o_k
    const float c = fmaf(fp, csp, t1 * t2);     // cell state (unscaled)
    const float u = rcp_f(1.0f + __expf(-2.0f * c));            // sig(2c)
    const float hn = fmaf(2.0f, u, -1.0f) * op; // o * tanh(c)
    const int wslot = t & 7;
    if (lane < HS) { lds_h[wslot][lane] = hn; lds_c[wslot][lane] = c; }
    __threadfence_block();                          // release
    if (lane == 0)
      __hip_atomic_store(&lds_seq[wslot], t, __ATOMIC_RELAXED,
                         __HIP_MEMORY_SCOPE_WORKGROUP);
    if (lane < HS) hout[(size_t)t * HS + lane] = hn;
    t += 4;
  }
}

// ----------------------------- K5: output heads ------------------------------
__global__ __launch_bounds__(256) void k_heads(
    const float* __restrict__ hbuf,
    const float* __restrict__ W_pfc, const float* __restrict__ b_pfc,
    const float* __restrict__ W_mu, const float* __restrict__ b_mu,
    const float* __restrict__ W_ls, const float* __restrict__ b_ls,
    float* __restrict__ mu_out, float* __restrict__ lso_out,
    float* __restrict__ ls_out) {
  __shared__ float wp[HS * HS], bp[HS], wm[NOUT * HS], bm[NOUT], wl[NOUT * HS], bl[NOUT];
  const int tid = threadIdx.x;
  for (int i = tid; i < HS * HS; i += 256) wp[i] = W_pfc[i];
  for (int i = tid; i < NOUT * HS; i += 256) { wm[i] = W_mu[i]; wl[i] = W_ls[i]; }
  if (tid < HS) bp[tid] = b_pfc[tid];
  if (tid < NOUT) { bm[tid] = b_mu[tid]; bl[tid] = b_ls[tid]; }
  __syncthreads();
  const int t = blockIdx.x * 256 + tid;
  float hr[HS];
  {
    const float4* hp4 = reinterpret_cast<const float4*>(hbuf + (size_t)t * HS);
#pragma unroll
    for (int q = 0; q < HS / 4; ++q) {
      const float4 h4 = hp4[q];
      hr[q * 4 + 0] = h4.x; hr[q * 4 + 1] = h4.y;
      hr[q * 4 + 2] = h4.z; hr[q * 4 + 3] = h4.w;
    }
  }
  float x[HS];
#pragma unroll
  for (int h = 0; h < HS; ++h) {
    float a = bp[h];
#pragma unroll
    for (int k = 0; k < HS; ++k) a = fmaf(hr[k], wp[h * HS + k], a);
    x[h] = tanh_f(a);
  }
  float4* mo4 = reinterpret_cast<float4*>(mu_out + (size_t)t * NOUT);
  float4* lo4 = reinterpret_cast<float4*>(lso_out + (size_t)t * NOUT);
  float4* lb4 = reinterpret_cast<float4*>(ls_out + (size_t)t * NOUT);
#pragma unroll
  for (int m = 0; m < NOUT; m += 4) {
    float4 mu4, lsb4, lso4;
    float am[4], bm_[4];
#pragma unroll
    for (int q = 0; q < 4; ++q) { am[q] = bm[m + q]; bm_[q] = bl[m + q]; }
#pragma unroll
    for (int k = 0; k < HS; ++k) {
      const float xv = x[k];
#pragma unroll
      for (int q = 0; q < 4; ++q) {
        am[q]  = fmaf(xv, wm[(m + q) * HS + k], am[q]);
        bm_[q] = fmaf(xv, wl[(m + q) * HS + k], bm_[q]);
      }
    }
    mu4.x = tanh_f(am[0]); mu4.y = tanh_f(am[1]);
    mu4.z = tanh_f(am[2]); mu4.w = tanh_f(am[3]);
    lsb4.x = bm_[0]; lsb4.y = bm_[1]; lsb4.z = bm_[2]; lsb4.w = bm_[3];
    lso4.x = __expf(fmaxf(bm_[0], 0.0f) - 2.0f);
    lso4.y = __expf(fmaxf(bm_[1], 0.0f) - 2.0f);
    lso4.z = __expf(fmaxf(bm_[2], 0.0f) - 2.0f);
    lso4.w = __expf(fmaxf(bm_[3], 0.0f) - 2.0f);
    mo4[m / 4] = mu4; lb4[m / 4] = lsb4; lo4[m / 4] = lso4;
  }
}

// ---------------------------------------------------------------------------
extern "C" void kernel_launch(void* const* d_in, const int* in_sizes, int n_in,
                              void* d_out, int out_size, void* d_ws, size_t ws_size,
                              hipStream_t stream) {
  const float* self_in = (const float*)d_in[0];
  const float* ally_in = (const float*)d_in[1];
  const int*   seg     = (const int*)d_in[2];
  const float* W_self  = (const float*)d_in[3];
  const float* b_self  = (const float*)d_in[4];
  const float* W_ally  = (const float*)d_in[5];
  const float* b_ally  = (const float*)d_in[6];
  const float* W_cat   = (const float*)d_in[7];
  const float* b_cat   = (const float*)d_in[8];
  const float* W_ih    = (const float*)d_in[9];
  const float* W_hh    = (const float*)d_in[10];
  const float* b_ih    = (const float*)d_in[11];
  const float* b_hh    = (const float*)d_in[12];
  const float* W_pfc   = (const float*)d_in[13];
  const float* b_pfc   = (const float*)d_in[14];
  const float* W_vfc   = (const float*)d_in[15];
  const float* b_vfc   = (const float*)d_in[16];
  const float* W_mu    = (const float*)d_in[17];
  const float* b_mu    = (const float*)d_in[18];
  const float* W_ls    = (const float*)d_in[19];
  const float* b_ls    = (const float*)d_in[20];
  const float* W_v     = (const float*)d_in[21];
  const float* b_v     = (const float*)d_in[22];
  const float* h0      = (const float*)d_in[23];
  const float* c0      = (const float*)d_in[24];
  float* out = (float*)d_out;

  // workspace layout (bytes): start[8193] | avg[T*20] | xg[T*80] | hbuf[T*20]
  char* ws = (char*)d_ws;
  int*   start = (int*)(ws);
  float* avg   = (float*)(ws + 36864);
  float* xg    = (float*)(ws + 692224);
  float* hbuf  = (float*)(ws + 3313664);   // total ~3.97 MB

  // output layout: mu[T*16] | log_std_out[T*16] | v[T] | log_std[T*16]
  float* mu_out  = out;
  float* lso_out = out + 131072;
  float* v_out   = out + 262144;
  float* ls_out  = out + 270336;

  k_bounds<<<(T_STEPS + 256) / 256, 256, 0, stream>>>(seg, start);
  k_segmean<<<T_STEPS, 64, 0, stream>>>(ally_in, start, W_ally, b_ally, avg);
  k_feats<<<T_STEPS / 256, 256, 0, stream>>>(self_in, avg, W_self, b_self,
                                             W_cat, b_cat, W_ih, b_ih, b_hh,
                                             W_vfc, b_vfc, W_v, b_v, xg, v_out);
  k_lstm<<<1, 256, 0, stream>>>(xg, W_hh, h0, c0, hbuf);
  k_heads<<<T_STEPS / 256, 256, 0, stream>>>(hbuf, W_pfc, b_pfc, W_mu, b_mu,
                                             W_ls, b_ls, mu_out, lso_out, ls_out);
}

// Round 7
// 1771.904 us; speedup vs baseline: 1.7116x; 1.7116x over previous
//
#include <hip/hip_runtime.h>
#include <hip/hip_bf16.h>

// ---------------------------------------------------------------------------
// Model: self/ally tanh-Linear encoders -> segment mean -> cat MLP ->
//        8192-step LSTM (H=20) -> policy/value heads.
//   k_bounds  : segment start offsets via binary search
//   k_segmean : 1 wave/segment; coalesced 64-row LDS tiles; W via scalar loads
//   k_feats   : 256-thr blocks; xg written float4 (bias included)
//   k_lstm    : SINGLE WAVE (R4 structure: ring reverted -- LDS handoff cost
//               825 cyc/step > in-register 507). Dots via v_pk_fma_f32
//               (packed fp32, inline asm) with h as SGPR pairs from readlane.
//   k_heads   : 256-thr blocks, float4 loads/stores
// ---------------------------------------------------------------------------

#define T_STEPS 8192
#define TOTAL_ROWS 1048576
#define DSELF 128
#define DALLY 64
#define HS 20
#define NOUT 16

typedef float v2f __attribute__((ext_vector_type(2)));

__device__ __forceinline__ float rcp_f(float x) { return __builtin_amdgcn_rcpf(x); }
__device__ __forceinline__ float sigm_f(float x) { return rcp_f(1.0f + __expf(-x)); }
// tanh(x) = 2*sigmoid(2x) - 1 ; saturates correctly at +-inf
__device__ __forceinline__ float tanh_f(float x) { return fmaf(2.0f, sigm_f(2.0f * x), -1.0f); }

// packed fp32 FMA: acc.{lo,hi} += w.{lo,hi} * h.{lo,hi}. h forced to an SGPR
// pair (readlane results are uniform; pairing costs SALU movs on the idle
// scalar pipe). One scalar operand per VALU instr -- legal.
__device__ __forceinline__ v2f pk_fma(v2f acc, v2f w, v2f h) {
  asm("v_pk_fma_f32 %0, %1, %2, %0" : "+v"(acc) : "v"(w), "s"(h));
  return acc;
}
__device__ __forceinline__ v2f pk_add(v2f a, v2f b) {
  v2f d;
  asm("v_pk_add_f32 %0, %1, %2" : "=v"(d) : "v"(a), "v"(b));
  return d;
}

// --------------------------- K1: segment boundaries -------------------------
__global__ void k_bounds(const int* __restrict__ seg, int* __restrict__ start) {
  int s = blockIdx.x * blockDim.x + threadIdx.x;
  if (s > T_STEPS) return;
  if (s == T_STEPS) { start[s] = TOTAL_ROWS; return; }
  int lo = 0, hi = TOTAL_ROWS;
  while (lo < hi) {
    int mid = (lo + hi) >> 1;
    if (seg[mid] < s) lo = mid + 1; else hi = mid;
  }
  start[s] = lo;
}

// ------------------- K2: fused ally tanh-linear + segment mean --------------
// one wave per segment. Rows staged through LDS in 64-row tiles so global
// loads are fully coalesced (wave reads 1KB contiguous per instruction).
__global__ __launch_bounds__(64) void k_segmean(
    const float* __restrict__ ally, const int* __restrict__ start,
    const float* __restrict__ W_ally, const float* __restrict__ b_ally,
    float* __restrict__ avg) {
  __shared__ float tile[64][DALLY + 2];
  __shared__ float red[64][HS + 1];
  const int lane = threadIdx.x;
  const int s = blockIdx.x;
  const int r0 = start[s], r1 = start[s + 1];
  float acc[HS];
#pragma unroll
  for (int h = 0; h < HS; ++h) acc[h] = 0.0f;
  for (int base = r0; base < r1; base += 64) {
    const int m = min(64, r1 - base);
    __syncthreads();  // protect tile from previous iteration's readers
    for (int idx = lane; idx < m * 16; idx += 64) {
      const int rr = idx >> 4, cc = (idx & 15) << 2;
      const float4 v = *reinterpret_cast<const float4*>(
          ally + (size_t)(base + rr) * DALLY + cc);
      *reinterpret_cast<float2*>(&tile[rr][cc])     = make_float2(v.x, v.y);
      *reinterpret_cast<float2*>(&tile[rr][cc + 2]) = make_float2(v.z, v.w);
    }
    __syncthreads();
    if (lane < m) {
      float dot[HS];
#pragma unroll
      for (int h = 0; h < HS; ++h) dot[h] = b_ally[h];  // uniform -> SGPR
#pragma unroll
      for (int j = 0; j < DALLY; j += 4) {
        const float2 xa = *reinterpret_cast<const float2*>(&tile[lane][j]);
        const float2 xb = *reinterpret_cast<const float2*>(&tile[lane][j + 2]);
#pragma unroll
        for (int h = 0; h < HS; ++h) {
          const float4 w = *reinterpret_cast<const float4*>(&W_ally[h * DALLY + j]);
          dot[h] = fmaf(xa.x, w.x, dot[h]);
          dot[h] = fmaf(xa.y, w.y, dot[h]);
          dot[h] = fmaf(xb.x, w.z, dot[h]);
          dot[h] = fmaf(xb.y, w.w, dot[h]);
        }
      }
#pragma unroll
      for (int h = 0; h < HS; ++h) acc[h] += tanh_f(dot[h]);
    }
  }
#pragma unroll
  for (int h = 0; h < HS; ++h) red[lane][h] = acc[h];
  __syncthreads();
  if (lane < HS) {
    float t = 0.0f;
    for (int l = 0; l < 64; ++l) t += red[l][lane];
    avg[(size_t)s * HS + lane] = t / (float)(r1 - r0);
  }
}

// ------------- K3: per-timestep features: s, cat, xg, value head ------------
__global__ __launch_bounds__(256) void k_feats(
    const float* __restrict__ self_in, const float* __restrict__ avg,
    const float* __restrict__ W_self, const float* __restrict__ b_self,
    const float* __restrict__ W_cat, const float* __restrict__ b_cat,
    const float* __restrict__ W_ih, const float* __restrict__ b_ih,
    const float* __restrict__ b_hh,
    const float* __restrict__ W_vfc, const float* __restrict__ b_vfc,
    const float* __restrict__ W_v, const float* __restrict__ b_v,
    float* __restrict__ xg, float* __restrict__ v_out) {
  __shared__ float s_ws[HS * DSELF];
  __shared__ float s_bs[HS];
  __shared__ float s_wc[HS * 2 * HS];
  __shared__ float s_bc[HS];
  __shared__ float s_wih[4 * HS * HS];
  __shared__ float s_bih[4 * HS];
  __shared__ float s_wv[HS * HS];
  __shared__ float s_bv[HS];
  __shared__ float s_wvv[HS];
  __shared__ float s_bvs;
  const int tid = threadIdx.x;
  for (int i = tid; i < HS * DSELF; i += 256) s_ws[i] = W_self[i];
  for (int i = tid; i < HS * 2 * HS; i += 256) s_wc[i] = W_cat[i];
  for (int i = tid; i < 4 * HS * HS; i += 256) s_wih[i] = W_ih[i];
  for (int i = tid; i < HS * HS; i += 256) s_wv[i] = W_vfc[i];
  if (tid < HS) {
    s_bs[tid] = b_self[tid]; s_bc[tid] = b_cat[tid];
    s_bv[tid] = b_vfc[tid];  s_wvv[tid] = W_v[tid];
  }
  if (tid < 4 * HS) s_bih[tid] = b_ih[tid] + b_hh[tid];
  if (tid == 0) s_bvs = b_v[0];
  __syncthreads();

  const int t = blockIdx.x * 256 + tid;
  const float* srow = self_in + (size_t)t * DSELF;
  float acc[HS];
#pragma unroll
  for (int h = 0; h < HS; ++h) acc[h] = s_bs[h];
  for (int j = 0; j < DSELF / 4; ++j) {
    const float4 x = *reinterpret_cast<const float4*>(srow + j * 4);
#pragma unroll
    for (int h = 0; h < HS; ++h) {
      const float4 w = *reinterpret_cast<const float4*>(&s_ws[h * DSELF + j * 4]);
      acc[h] = fmaf(x.x, w.x, acc[h]);
      acc[h] = fmaf(x.y, w.y, acc[h]);
      acc[h] = fmaf(x.z, w.z, acc[h]);
      acc[h] = fmaf(x.w, w.w, acc[h]);
    }
  }
  float sv[HS], av[HS];
#pragma unroll
  for (int h = 0; h < HS; ++h) sv[h] = tanh_f(acc[h]);
  {
    const float4* ap = reinterpret_cast<const float4*>(avg + (size_t)t * HS);
#pragma unroll
    for (int q = 0; q < HS / 4; ++q) {
      const float4 a4 = ap[q];
      av[q * 4 + 0] = a4.x; av[q * 4 + 1] = a4.y;
      av[q * 4 + 2] = a4.z; av[q * 4 + 3] = a4.w;
    }
  }
  float cat[HS];
#pragma unroll
  for (int h = 0; h < HS; ++h) {
    float a = s_bc[h];
#pragma unroll
    for (int j = 0; j < HS; ++j) a = fmaf(sv[j], s_wc[h * 2 * HS + j], a);
#pragma unroll
    for (int j = 0; j < HS; ++j) a = fmaf(av[j], s_wc[h * 2 * HS + HS + j], a);
    cat[h] = tanh_f(a);
  }
  // xg written as float4 groups of gate rows (i,f,g,o row-major order 0..79)
#pragma unroll 2
  for (int jj = 0; jj < 4 * HS; jj += 4) {
    float a0 = s_bih[jj], a1 = s_bih[jj + 1], a2 = s_bih[jj + 2], a3 = s_bih[jj + 3];
#pragma unroll
    for (int k = 0; k < HS; ++k) {
      const float cv = cat[k];
      a0 = fmaf(cv, s_wih[(jj + 0) * HS + k], a0);
      a1 = fmaf(cv, s_wih[(jj + 1) * HS + k], a1);
      a2 = fmaf(cv, s_wih[(jj + 2) * HS + k], a2);
      a3 = fmaf(cv, s_wih[(jj + 3) * HS + k], a3);
    }
    float4 o4; o4.x = a0; o4.y = a1; o4.z = a2; o4.w = a3;
    *reinterpret_cast<float4*>(&xg[(size_t)t * 80 + jj]) = o4;
  }
  float vacc = s_bvs;
#pragma unroll
  for (int h = 0; h < HS; ++h) {
    float a = s_bv[h];
#pragma unroll
    for (int k = 0; k < HS; ++k) a = fmaf(cat[k], s_wv[h * HS + k], a);
    vacc = fmaf(tanh_f(a), s_wvv[h], vacc);
  }
  v_out[t] = vacc;
}

// ----------------------------- K4: LSTM scan --------------------------------
// Single wave (R4 structure). Pass1: lanes 0-19 -> i rows, lanes 32-51 -> f
// rows; pass2: lanes 0-19 -> g rows (local), lanes 32-51 -> o rows. f,o cross
// to lanes 0-19 via v_permlane32_swap (VALU). h broadcast via readlane->SGPR;
// dots are v_pk_fma_f32 with h as SGPR pairs (halves dot issue: 40 FMA ->
// 20 pk-FMA). Accumulators seeded with {xg,0} so no trailing dependent add.
// 4x unroll, 4-deep xg prefetch (tail reads spill <=1280B into hbuf region:
// valid memory, values never consumed).
#define LSTM_STEP(X1, X2, K)                                                  \
  do {                                                                        \
    v2f pA = {(X1), 0.0f}, pB = {0.0f, 0.0f};                                 \
    v2f qA = {(X2), 0.0f}, qB = {0.0f, 0.0f};                                 \
    _Pragma("unroll") for (int j = 0; j < 10; j += 2) {                       \
      const v2f h2a = {hs[2 * j],     hs[2 * j + 1]};                         \
      const v2f h2b = {hs[2 * j + 2], hs[2 * j + 3]};                         \
      pA = pk_fma(pA, wa2[j],     h2a);                                       \
      qA = pk_fma(qA, wb2[j],     h2a);                                       \
      pB = pk_fma(pB, wa2[j + 1], h2b);                                       \
      qB = pk_fma(qB, wb2[j + 1], h2b);                                       \
    }                                                                         \
    pA = pk_add(pA, pB);                                                      \
    qA = pk_add(qA, qB);                                                      \
    const float a1 = pA.x + pA.y;                                             \
    const float a2 = qA.x + qA.y;                                             \
    (X1) = px1[(K + 4) * 80];                                                 \
    (X2) = px2[(K + 4) * 80];                                                 \
    const float t1 = rcp_f(1.0f + __expf(-a1));                 /* i | f */   \
    const float t2 = fmaf(A, rcp_f(1.0f + __expf(-S * a2)), B); /* g | o */   \
    auto rfp = __builtin_amdgcn_permlane32_swap(                              \
        __float_as_uint(t1), __float_as_uint(t1), false, false);              \
    auto rop = __builtin_amdgcn_permlane32_swap(                              \
        __float_as_uint(t2), __float_as_uint(t2), false, false);              \
    const float fp = __uint_as_float(rfp[1]);   /* lane k: f_k */             \
    const float op = __uint_as_float(rop[1]);   /* lane k: o_k */             \
    c = fmaf(fp, c, t1 * t2);                                                 \
    const float op2 = op + op;                  /* off-path, under exp */     \
    const float u = rcp_f(1.0f + __expf(-2.0f * c));            /* sig(2c) */ \
    const float hn = fmaf(op2, u, -op);         /* o * tanh(c) */             \
    if (lane < HS) hp[(K)*HS] = hn;                                           \
    const unsigned hu = __float_as_uint(hn);                                  \
    _Pragma("unroll") for (int j = 0; j < HS; ++j)                            \
        hs[j] = __uint_as_float(__builtin_amdgcn_readlane(hu, j));            \
  } while (0)

__global__ __launch_bounds__(64) void k_lstm(
    const float* __restrict__ xg, const float* __restrict__ Whh,
    const float* __restrict__ h0, const float* __restrict__ c0,
    float* __restrict__ hout) {
  const int lane = threadIdx.x;
  const int kk = lane & 31;
  const int kc = kk < HS ? kk : HS - 1;            // clamp dup lanes
  const int r1 = kc + ((lane >= 32) ? HS : 0);     // i rows | f rows
  const int r2 = r1 + 2 * HS;                      // g rows | o rows

  // pass2 nonlinearity: tanh (g) on lanes<32, sigmoid (o) on lanes>=32
  const float S = (lane < 32) ? 2.0f : 1.0f;
  const float A = (lane < 32) ? 2.0f : 1.0f;
  const float B = (lane < 32) ? -1.0f : 0.0f;

  // W_hh rows as packed pairs (rows are 20 floats = 80B -> 8B aligned)
  v2f wa2[10], wb2[10];
  {
    const v2f* ra = reinterpret_cast<const v2f*>(Whh + (size_t)r1 * HS);
    const v2f* rb = reinterpret_cast<const v2f*>(Whh + (size_t)r2 * HS);
#pragma unroll
    for (int j = 0; j < 10; ++j) { wa2[j] = ra[j]; wb2[j] = rb[j]; }
  }

  float hs[HS];
#pragma unroll
  for (int j = 0; j < HS; ++j) hs[j] = h0[j];      // uniform -> s_load
  float c = c0[kc];                                // real c on lanes<20

  const float* px1 = xg + r1;
  const float* px2 = xg + r2;
  float x10 = px1[0],       x20 = px2[0];
  float x11 = px1[1 * 80],  x21 = px2[1 * 80];
  float x12 = px1[2 * 80],  x22 = px2[2 * 80];
  float x13 = px1[3 * 80],  x23 = px2[3 * 80];
  float* hp = hout + lane;

  for (int t = 0; t < T_STEPS; t += 4) {
    LSTM_STEP(x10, x20, 0);
    LSTM_STEP(x11, x21, 1);
    LSTM_STEP(x12, x22, 2);
    LSTM_STEP(x13, x23, 3);
    px1 += 4 * 80; px2 += 4 * 80; hp += 4 * HS;
  }
}

// ----------------------------- K5: output heads ------------------------------
__global__ __launch_bounds__(256) void k_heads(
    const float* __restrict__ hbuf,
    const float* __restrict__ W_pfc, const float* __restrict__ b_pfc,
    const float* __restrict__ W_mu, const float* __restrict__ b_mu,
    const float* __restrict__ W_ls, const float* __restrict__ b_ls,
    float* __restrict__ mu_out, float* __restrict__ lso_out,
    float* __restrict__ ls_out) {
  __shared__ float wp[HS * HS], bp[HS], wm[NOUT * HS], bm[NOUT], wl[NOUT * HS], bl[NOUT];
  const int tid = threadIdx.x;
  for (int i = tid; i < HS * HS; i += 256) wp[i] = W_pfc[i];
  for (int i = tid; i < NOUT * HS; i += 256) { wm[i] = W_mu[i]; wl[i] = W_ls[i]; }
  if (tid < HS) bp[tid] = b_pfc[tid];
  if (tid < NOUT) { bm[tid] = b_mu[tid]; bl[tid] = b_ls[tid]; }
  __syncthreads();
  const int t = blockIdx.x * 256 + tid;
  float hr[HS];
  {
    const float4* hp4 = reinterpret_cast<const float4*>(hbuf + (size_t)t * HS);
#pragma unroll
    for (int q = 0; q < HS / 4; ++q) {
      const float4 h4 = hp4[q];
      hr[q * 4 + 0] = h4.x; hr[q * 4 + 1] = h4.y;
      hr[q * 4 + 2] = h4.z; hr[q * 4 + 3] = h4.w;
    }
  }
  float x[HS];
#pragma unroll
  for (int h = 0; h < HS; ++h) {
    float a = bp[h];
#pragma unroll
    for (int k = 0; k < HS; ++k) a = fmaf(hr[k], wp[h * HS + k], a);
    x[h] = tanh_f(a);
  }
  float4* mo4 = reinterpret_cast<float4*>(mu_out + (size_t)t * NOUT);
  float4* lo4 = reinterpret_cast<float4*>(lso_out + (size_t)t * NOUT);
  float4* lb4 = reinterpret_cast<float4*>(ls_out + (size_t)t * NOUT);
#pragma unroll
  for (int m = 0; m < NOUT; m += 4) {
    float4 mu4, lsb4, lso4;
    float am[4], bm_[4];
#pragma unroll
    for (int q = 0; q < 4; ++q) { am[q] = bm[m + q]; bm_[q] = bl[m + q]; }
#pragma unroll
    for (int k = 0; k < HS; ++k) {
      const float xv = x[k];
#pragma unroll
      for (int q = 0; q < 4; ++q) {
        am[q]  = fmaf(xv, wm[(m + q) * HS + k], am[q]);
        bm_[q] = fmaf(xv, wl[(m + q) * HS + k], bm_[q]);
      }
    }
    mu4.x = tanh_f(am[0]); mu4.y = tanh_f(am[1]);
    mu4.z = tanh_f(am[2]); mu4.w = tanh_f(am[3]);
    lsb4.x = bm_[0]; lsb4.y = bm_[1]; lsb4.z = bm_[2]; lsb4.w = bm_[3];
    lso4.x = __expf(fmaxf(bm_[0], 0.0f) - 2.0f);
    lso4.y = __expf(fmaxf(bm_[1], 0.0f) - 2.0f);
    lso4.z = __expf(fmaxf(bm_[2], 0.0f) - 2.0f);
    lso4.w = __expf(fmaxf(bm_[3], 0.0f) - 2.0f);
    mo4[m / 4] = mu4; lb4[m / 4] = lsb4; lo4[m / 4] = lso4;
  }
}

// ---------------------------------------------------------------------------
extern "C" void kernel_launch(void* const* d_in, const int* in_sizes, int n_in,
                              void* d_out, int out_size, void* d_ws, size_t ws_size,
                              hipStream_t stream) {
  const float* self_in = (const float*)d_in[0];
  const float* ally_in = (const float*)d_in[1];
  const int*   seg     = (const int*)d_in[2];
  const float* W_self  = (const float*)d_in[3];
  const float* b_self  = (const float*)d_in[4];
  const float* W_ally  = (const float*)d_in[5];
  const float* b_ally  = (const float*)d_in[6];
  const float* W_cat   = (const float*)d_in[7];
  const float* b_cat   = (const float*)d_in[8];
  const float* W_ih    = (const float*)d_in[9];
  const float* W_hh    = (const float*)d_in[10];
  const float* b_ih    = (const float*)d_in[11];
  const float* b_hh    = (const float*)d_in[12];
  const float* W_pfc   = (const float*)d_in[13];
  const float* b_pfc   = (const float*)d_in[14];
  const float* W_vfc   = (const float*)d_in[15];
  const float* b_vfc   = (const float*)d_in[16];
  const float* W_mu    = (const float*)d_in[17];
  const float* b_mu    = (const float*)d_in[18];
  const float* W_ls    = (const float*)d_in[19];
  const float* b_ls    = (const float*)d_in[20];
  const float* W_v     = (const float*)d_in[21];
  const float* b_v     = (const float*)d_in[22];
  const float* h0      = (const float*)d_in[23];
  const float* c0      = (const float*)d_in[24];
  float* out = (float*)d_out;

  // workspace layout (bytes): start[8193] | avg[T*20] | xg[T*80] | hbuf[T*20]
  char* ws = (char*)d_ws;
  int*   start = (int*)(ws);
  float* avg   = (float*)(ws + 36864);
  float* xg    = (float*)(ws + 692224);
  float* hbuf  = (float*)(ws + 3313664);   // total ~3.97 MB

  // output layout: mu[T*16] | log_std_out[T*16] | v[T] | log_std[T*16]
  float* mu_out  = out;
  float* lso_out = out + 131072;
  float* v_out   = out + 262144;
  float* ls_out  = out + 270336;

  k_bounds<<<(T_STEPS + 256) / 256, 256, 0, stream>>>(seg, start);
  k_segmean<<<T_STEPS, 64, 0, stream>>>(ally_in, start, W_ally, b_ally, avg);
  k_feats<<<T_STEPS / 256, 256, 0, stream>>>(self_in, avg, W_self, b_self,
                                             W_cat, b_cat, W_ih, b_ih, b_hh,
                                             W_vfc, b_vfc, W_v, b_v, xg, v_out);
  k_lstm<<<1, 64, 0, stream>>>(xg, W_hh, h0, c0, hbuf);
  k_heads<<<T_STEPS / 256, 256, 0, stream>>>(hbuf, W_pfc, b_pfc, W_mu, b_mu,
                                             W_ls, b_ls, mu_out, lso_out, ls_out);
}

// Round 8
// 1653.289 us; speedup vs baseline: 1.8344x; 1.0717x over previous
//
#include <hip/hip_runtime.h>
#include <hip/hip_bf16.h>

// ---------------------------------------------------------------------------
// Model: self/ally tanh-Linear encoders -> segment mean -> cat MLP ->
//        8192-step LSTM (H=20) -> policy/value heads.
//   k_bounds  : segment start offsets via binary search
//   k_segmean : 1 wave/segment; coalesced 64-row LDS tiles; W via scalar loads
//   k_feats   : 256-thr blocks; xg written float4, PRE-SCALED by log2e
//               (i,f,o rows) / 2*log2e (g rows) so k_lstm's nonlinearities
//               are pure rcp(1+exp2(-a)) with free negation modifiers.
//   k_lstm    : single wave; i|f on lanes 0-19|32-51 (pass1), g|o (pass2);
//               f,o cross via v_permlane32_swap; dots via v_pk_fma_f32 with
//               h as SGPR pairs; SCALED CELL cs = 2*log2e*c (exact algebra);
//               8x unroll + 8-deep xg prefetch.
//   k_heads   : 256-thr blocks, float4 loads/stores
// ---------------------------------------------------------------------------

#define T_STEPS 8192
#define TOTAL_ROWS 1048576
#define DSELF 128
#define DALLY 64
#define HS 20
#define NOUT 16
#define L2E 1.44269504088896340736f

typedef float v2f __attribute__((ext_vector_type(2)));

__device__ __forceinline__ float rcp_f(float x) { return __builtin_amdgcn_rcpf(x); }
__device__ __forceinline__ float sigm_f(float x) { return rcp_f(1.0f + __expf(-x)); }
// tanh(x) = 2*sigmoid(2x) - 1 ; saturates correctly at +-inf
__device__ __forceinline__ float tanh_f(float x) { return fmaf(2.0f, sigm_f(2.0f * x), -1.0f); }
// 1/(1+2^-x): exp2 with free neg input modifier, no leading multiply
__device__ __forceinline__ float sig2_f(float x) {
  return rcp_f(1.0f + __builtin_amdgcn_exp2f(-x));
}

// packed fp32 FMA: acc.{lo,hi} += w.{lo,hi} * h.{lo,hi}; h is an SGPR pair.
__device__ __forceinline__ v2f pk_fma(v2f acc, v2f w, v2f h) {
  asm("v_pk_fma_f32 %0, %1, %2, %0" : "+v"(acc) : "v"(w), "s"(h));
  return acc;
}
__device__ __forceinline__ v2f pk_add(v2f a, v2f b) {
  v2f d;
  asm("v_pk_add_f32 %0, %1, %2" : "=v"(d) : "v"(a), "v"(b));
  return d;
}

// --------------------------- K1: segment boundaries -------------------------
__global__ void k_bounds(const int* __restrict__ seg, int* __restrict__ start) {
  int s = blockIdx.x * blockDim.x + threadIdx.x;
  if (s > T_STEPS) return;
  if (s == T_STEPS) { start[s] = TOTAL_ROWS; return; }
  int lo = 0, hi = TOTAL_ROWS;
  while (lo < hi) {
    int mid = (lo + hi) >> 1;
    if (seg[mid] < s) lo = mid + 1; else hi = mid;
  }
  start[s] = lo;
}

// ------------------- K2: fused ally tanh-linear + segment mean --------------
__global__ __launch_bounds__(64) void k_segmean(
    const float* __restrict__ ally, const int* __restrict__ start,
    const float* __restrict__ W_ally, const float* __restrict__ b_ally,
    float* __restrict__ avg) {
  __shared__ float tile[64][DALLY + 2];
  __shared__ float red[64][HS + 1];
  const int lane = threadIdx.x;
  const int s = blockIdx.x;
  const int r0 = start[s], r1 = start[s + 1];
  float acc[HS];
#pragma unroll
  for (int h = 0; h < HS; ++h) acc[h] = 0.0f;
  for (int base = r0; base < r1; base += 64) {
    const int m = min(64, r1 - base);
    __syncthreads();  // protect tile from previous iteration's readers
    for (int idx = lane; idx < m * 16; idx += 64) {
      const int rr = idx >> 4, cc = (idx & 15) << 2;
      const float4 v = *reinterpret_cast<const float4*>(
          ally + (size_t)(base + rr) * DALLY + cc);
      *reinterpret_cast<float2*>(&tile[rr][cc])     = make_float2(v.x, v.y);
      *reinterpret_cast<float2*>(&tile[rr][cc + 2]) = make_float2(v.z, v.w);
    }
    __syncthreads();
    if (lane < m) {
      float dot[HS];
#pragma unroll
      for (int h = 0; h < HS; ++h) dot[h] = b_ally[h];  // uniform -> SGPR
#pragma unroll
      for (int j = 0; j < DALLY; j += 4) {
        const float2 xa = *reinterpret_cast<const float2*>(&tile[lane][j]);
        const float2 xb = *reinterpret_cast<const float2*>(&tile[lane][j + 2]);
#pragma unroll
        for (int h = 0; h < HS; ++h) {
          const float4 w = *reinterpret_cast<const float4*>(&W_ally[h * DALLY + j]);
          dot[h] = fmaf(xa.x, w.x, dot[h]);
          dot[h] = fmaf(xa.y, w.y, dot[h]);
          dot[h] = fmaf(xb.x, w.z, dot[h]);
          dot[h] = fmaf(xb.y, w.w, dot[h]);
        }
      }
#pragma unroll
      for (int h = 0; h < HS; ++h) acc[h] += tanh_f(dot[h]);
    }
  }
#pragma unroll
  for (int h = 0; h < HS; ++h) red[lane][h] = acc[h];
  __syncthreads();
  if (lane < HS) {
    float t = 0.0f;
    for (int l = 0; l < 64; ++l) t += red[l][lane];
    avg[(size_t)s * HS + lane] = t / (float)(r1 - r0);
  }
}

// ------------- K3: per-timestep features: s, cat, xg(scaled), value ---------
__global__ __launch_bounds__(256) void k_feats(
    const float* __restrict__ self_in, const float* __restrict__ avg,
    const float* __restrict__ W_self, const float* __restrict__ b_self,
    const float* __restrict__ W_cat, const float* __restrict__ b_cat,
    const float* __restrict__ W_ih, const float* __restrict__ b_ih,
    const float* __restrict__ b_hh,
    const float* __restrict__ W_vfc, const float* __restrict__ b_vfc,
    const float* __restrict__ W_v, const float* __restrict__ b_v,
    float* __restrict__ xg, float* __restrict__ v_out) {
  __shared__ float s_ws[HS * DSELF];
  __shared__ float s_bs[HS];
  __shared__ float s_wc[HS * 2 * HS];
  __shared__ float s_bc[HS];
  __shared__ float s_wih[4 * HS * HS];
  __shared__ float s_bih[4 * HS];
  __shared__ float s_wv[HS * HS];
  __shared__ float s_bv[HS];
  __shared__ float s_wvv[HS];
  __shared__ float s_bvs;
  const int tid = threadIdx.x;
  for (int i = tid; i < HS * DSELF; i += 256) s_ws[i] = W_self[i];
  for (int i = tid; i < HS * 2 * HS; i += 256) s_wc[i] = W_cat[i];
  // exp2-folding: scale gate rows at staging. rows 40-59 (g) by 2*L2E,
  // others (i,f,o) by L2E. W_ih flat idx i -> row i/HS; g rows = [800,1200).
  for (int i = tid; i < 4 * HS * HS; i += 256) {
    const float sc = (i >= 800 && i < 1200) ? (2.0f * L2E) : L2E;
    s_wih[i] = W_ih[i] * sc;
  }
  for (int i = tid; i < HS * HS; i += 256) s_wv[i] = W_vfc[i];
  if (tid < HS) {
    s_bs[tid] = b_self[tid]; s_bc[tid] = b_cat[tid];
    s_bv[tid] = b_vfc[tid];  s_wvv[tid] = W_v[tid];
  }
  if (tid < 4 * HS) {
    const float sc = (tid >= 40 && tid < 60) ? (2.0f * L2E) : L2E;
    s_bih[tid] = (b_ih[tid] + b_hh[tid]) * sc;
  }
  if (tid == 0) s_bvs = b_v[0];
  __syncthreads();

  const int t = blockIdx.x * 256 + tid;
  const float* srow = self_in + (size_t)t * DSELF;
  float acc[HS];
#pragma unroll
  for (int h = 0; h < HS; ++h) acc[h] = s_bs[h];
  for (int j = 0; j < DSELF / 4; ++j) {
    const float4 x = *reinterpret_cast<const float4*>(srow + j * 4);
#pragma unroll
    for (int h = 0; h < HS; ++h) {
      const float4 w = *reinterpret_cast<const float4*>(&s_ws[h * DSELF + j * 4]);
      acc[h] = fmaf(x.x, w.x, acc[h]);
      acc[h] = fmaf(x.y, w.y, acc[h]);
      acc[h] = fmaf(x.z, w.z, acc[h]);
      acc[h] = fmaf(x.w, w.w, acc[h]);
    }
  }
  float sv[HS], av[HS];
#pragma unroll
  for (int h = 0; h < HS; ++h) sv[h] = tanh_f(acc[h]);
  {
    const float4* ap = reinterpret_cast<const float4*>(avg + (size_t)t * HS);
#pragma unroll
    for (int q = 0; q < HS / 4; ++q) {
      const float4 a4 = ap[q];
      av[q * 4 + 0] = a4.x; av[q * 4 + 1] = a4.y;
      av[q * 4 + 2] = a4.z; av[q * 4 + 3] = a4.w;
    }
  }
  float cat[HS];
#pragma unroll
  for (int h = 0; h < HS; ++h) {
    float a = s_bc[h];
#pragma unroll
    for (int j = 0; j < HS; ++j) a = fmaf(sv[j], s_wc[h * 2 * HS + j], a);
#pragma unroll
    for (int j = 0; j < HS; ++j) a = fmaf(av[j], s_wc[h * 2 * HS + HS + j], a);
    cat[h] = tanh_f(a);
  }
  // xg written as float4 groups of gate rows (scaled pre-activations)
#pragma unroll 2
  for (int jj = 0; jj < 4 * HS; jj += 4) {
    float a0 = s_bih[jj], a1 = s_bih[jj + 1], a2 = s_bih[jj + 2], a3 = s_bih[jj + 3];
#pragma unroll
    for (int k = 0; k < HS; ++k) {
      const float cv = cat[k];
      a0 = fmaf(cv, s_wih[(jj + 0) * HS + k], a0);
      a1 = fmaf(cv, s_wih[(jj + 1) * HS + k], a1);
      a2 = fmaf(cv, s_wih[(jj + 2) * HS + k], a2);
      a3 = fmaf(cv, s_wih[(jj + 3) * HS + k], a3);
    }
    float4 o4; o4.x = a0; o4.y = a1; o4.z = a2; o4.w = a3;
    *reinterpret_cast<float4*>(&xg[(size_t)t * 80 + jj]) = o4;
  }
  float vacc = s_bvs;
#pragma unroll
  for (int h = 0; h < HS; ++h) {
    float a = s_bv[h];
#pragma unroll
    for (int k = 0; k < HS; ++k) a = fmaf(cat[k], s_wv[h * HS + k], a);
    vacc = fmaf(tanh_f(a), s_wvv[h], vacc);
  }
  v_out[t] = vacc;
}

// ----------------------------- K4: LSTM scan --------------------------------
// Single wave, exp2-folded, scaled cell. Lane k<20: i_k,g_k; lane 32+k: f_k,o_k.
// Invariant: cs = 2*log2e*c. Update: cs' = f*cs + t1*t2s where t2s =
// 2*log2e*tanh(g_pre) = fma(4*L2E, sig2(a2), -2*L2E). u = sig2(cs) = sig(2c).
// hn = o*tanh(c) = fma(2o, u, -o). All exp2 args pre-scaled (xg + W rows).
#define LSTM_STEP(X1, X2, K)                                                  \
  do {                                                                        \
    v2f pA = {(X1), 0.0f}, pB = {0.0f, 0.0f};                                 \
    v2f qA = {(X2), 0.0f}, qB = {0.0f, 0.0f};                                 \
    _Pragma("unroll") for (int j = 0; j < 10; j += 2) {                       \
      const v2f h2a = {hs[2 * j],     hs[2 * j + 1]};                         \
      const v2f h2b = {hs[2 * j + 2], hs[2 * j + 3]};                         \
      pA = pk_fma(pA, wa2[j],     h2a);                                       \
      qA = pk_fma(qA, wb2[j],     h2a);                                       \
      pB = pk_fma(pB, wa2[j + 1], h2b);                                       \
      qB = pk_fma(qB, wb2[j + 1], h2b);                                       \
    }                                                                         \
    pA = pk_add(pA, pB);                                                      \
    qA = pk_add(qA, qB);                                                      \
    const float a1 = pA.x + pA.y;                                             \
    const float a2 = qA.x + qA.y;                                             \
    (X1) = px1[(K + 8) * 80];                                                 \
    (X2) = px2[(K + 8) * 80];                                                 \
    const float t1 = sig2_f(a1);                  /* i | f */                 \
    const float t2 = fmaf(Ac, sig2_f(a2), Bc);    /* 2L2E*tanh(g) | o */      \
    auto rfp = __builtin_amdgcn_permlane32_swap(                              \
        __float_as_uint(t1), __float_as_uint(t1), false, false);              \
    auto rop = __builtin_amdgcn_permlane32_swap(                              \
        __float_as_uint(t2), __float_as_uint(t2), false, false);              \
    const float fp = __uint_as_float(rfp[1]);     /* lane k: f_k */           \
    const float op = __uint_as_float(rop[1]);     /* lane k: o_k */           \
    cs = fmaf(fp, cs, t1 * t2);                   /* scaled cell */           \
    const float op2 = op + op;                    /* off-path */              \
    const float u = sig2_f(cs);                   /* sig(2c) */               \
    const float hn = fmaf(op2, u, -op);           /* o * tanh(c) */           \
    if (lane < HS) hp[(K)*HS] = hn;                                           \
    const unsigned hu = __float_as_uint(hn);                                  \
    _Pragma("unroll") for (int j = 0; j < HS; ++j)                            \
        hs[j] = __uint_as_float(__builtin_amdgcn_readlane(hu, j));            \
  } while (0)

__global__ __launch_bounds__(64) void k_lstm(
    const float* __restrict__ xg, const float* __restrict__ Whh,
    const float* __restrict__ h0, const float* __restrict__ c0,
    float* __restrict__ hout) {
  const int lane = threadIdx.x;
  const int kk = lane & 31;
  const int kc = kk < HS ? kk : HS - 1;            // clamp dup lanes
  const int r1 = kc + ((lane >= 32) ? HS : 0);     // i rows | f rows
  const int r2 = r1 + 2 * HS;                      // g rows | o rows

  // pass2: g lanes (<32): t2 = 2L2E*tanh ; o lanes (>=32): t2 = sigmoid
  const float Ac = (lane < 32) ? 4.0f * L2E : 1.0f;
  const float Bc = (lane < 32) ? -2.0f * L2E : 0.0f;
  // W_hh row scales: pass1 rows (i,f) sigmoid -> L2E; pass2 g -> 2L2E, o -> L2E
  const float s2v = (lane < 32) ? 2.0f * L2E : L2E;

  v2f wa2[10], wb2[10];
  {
    const v2f* ra = reinterpret_cast<const v2f*>(Whh + (size_t)r1 * HS);
    const v2f* rb = reinterpret_cast<const v2f*>(Whh + (size_t)r2 * HS);
#pragma unroll
    for (int j = 0; j < 10; ++j) {
      v2f a = ra[j], b = rb[j];
      a.x *= L2E; a.y *= L2E;
      b.x *= s2v; b.y *= s2v;
      wa2[j] = a; wb2[j] = b;
    }
  }

  float hs[HS];
#pragma unroll
  for (int j = 0; j < HS; ++j) hs[j] = h0[j];      // uniform -> s_load
  float cs = c0[kc] * (2.0f * L2E);                // scaled cell

  const float* px1 = xg + r1;
  const float* px2 = xg + r2;
  float x10 = px1[0 * 80], x20 = px2[0 * 80];
  float x11 = px1[1 * 80], x21 = px2[1 * 80];
  float x12 = px1[2 * 80], x22 = px2[2 * 80];
  float x13 = px1[3 * 80], x23 = px2[3 * 80];
  float x14 = px1[4 * 80], x24 = px2[4 * 80];
  float x15 = px1[5 * 80], x25 = px2[5 * 80];
  float x16 = px1[6 * 80], x26 = px2[6 * 80];
  float x17 = px1[7 * 80], x27 = px2[7 * 80];
  float* hp = hout + lane;

  // tail prefetch reads <=2560B past xg end: lands in hbuf region (valid
  // memory, values never consumed).
  for (int t = 0; t < T_STEPS; t += 8) {
    LSTM_STEP(x10, x20, 0);
    LSTM_STEP(x11, x21, 1);
    LSTM_STEP(x12, x22, 2);
    LSTM_STEP(x13, x23, 3);
    LSTM_STEP(x14, x24, 4);
    LSTM_STEP(x15, x25, 5);
    LSTM_STEP(x16, x26, 6);
    LSTM_STEP(x17, x27, 7);
    px1 += 8 * 80; px2 += 8 * 80; hp += 8 * HS;
  }
}

// ----------------------------- K5: output heads ------------------------------
__global__ __launch_bounds__(256) void k_heads(
    const float* __restrict__ hbuf,
    const float* __restrict__ W_pfc, const float* __restrict__ b_pfc,
    const float* __restrict__ W_mu, const float* __restrict__ b_mu,
    const float* __restrict__ W_ls, const float* __restrict__ b_ls,
    float* __restrict__ mu_out, float* __restrict__ lso_out,
    float* __restrict__ ls_out) {
  __shared__ float wp[HS * HS], bp[HS], wm[NOUT * HS], bm[NOUT], wl[NOUT * HS], bl[NOUT];
  const int tid = threadIdx.x;
  for (int i = tid; i < HS * HS; i += 256) wp[i] = W_pfc[i];
  for (int i = tid; i < NOUT * HS; i += 256) { wm[i] = W_mu[i]; wl[i] = W_ls[i]; }
  if (tid < HS) bp[tid] = b_pfc[tid];
  if (tid < NOUT) { bm[tid] = b_mu[tid]; bl[tid] = b_ls[tid]; }
  __syncthreads();
  const int t = blockIdx.x * 256 + tid;
  float hr[HS];
  {
    const float4* hp4 = reinterpret_cast<const float4*>(hbuf + (size_t)t * HS);
#pragma unroll
    for (int q = 0; q < HS / 4; ++q) {
      const float4 h4 = hp4[q];
      hr[q * 4 + 0] = h4.x; hr[q * 4 + 1] = h4.y;
      hr[q * 4 + 2] = h4.z; hr[q * 4 + 3] = h4.w;
    }
  }
  float x[HS];
#pragma unroll
  for (int h = 0; h < HS; ++h) {
    float a = bp[h];
#pragma unroll
    for (int k = 0; k < HS; ++k) a = fmaf(hr[k], wp[h * HS + k], a);
    x[h] = tanh_f(a);
  }
  float4* mo4 = reinterpret_cast<float4*>(mu_out + (size_t)t * NOUT);
  float4* lo4 = reinterpret_cast<float4*>(lso_out + (size_t)t * NOUT);
  float4* lb4 = reinterpret_cast<float4*>(ls_out + (size_t)t * NOUT);
#pragma unroll
  for (int m = 0; m < NOUT; m += 4) {
    float4 mu4, lsb4, lso4;
    float am[4], bm_[4];
#pragma unroll
    for (int q = 0; q < 4; ++q) { am[q] = bm[m + q]; bm_[q] = bl[m + q]; }
#pragma unroll
    for (int k = 0; k < HS; ++k) {
      const float xv = x[k];
#pragma unroll
      for (int q = 0; q < 4; ++q) {
        am[q]  = fmaf(xv, wm[(m + q) * HS + k], am[q]);
        bm_[q] = fmaf(xv, wl[(m + q) * HS + k], bm_[q]);
      }
    }
    mu4.x = tanh_f(am[0]); mu4.y = tanh_f(am[1]);
    mu4.z = tanh_f(am[2]); mu4.w = tanh_f(am[3]);
    lsb4.x = bm_[0]; lsb4.y = bm_[1]; lsb4.z = bm_[2]; lsb4.w = bm_[3];
    lso4.x = __expf(fmaxf(bm_[0], 0.0f) - 2.0f);
    lso4.y = __expf(fmaxf(bm_[1], 0.0f) - 2.0f);
    lso4.z = __expf(fmaxf(bm_[2], 0.0f) - 2.0f);
    lso4.w = __expf(fmaxf(bm_[3], 0.0f) - 2.0f);
    mo4[m / 4] = mu4; lb4[m / 4] = lsb4; lo4[m / 4] = lso4;
  }
}

// ---------------------------------------------------------------------------
extern "C" void kernel_launch(void* const* d_in, const int* in_sizes, int n_in,
                              void* d_out, int out_size, void* d_ws, size_t ws_size,
                              hipStream_t stream) {
  const float* self_in = (const float*)d_in[0];
  const float* ally_in = (const float*)d_in[1];
  const int*   seg     = (const int*)d_in[2];
  const float* W_self  = (const float*)d_in[3];
  const float* b_self  = (const float*)d_in[4];
  const float* W_ally  = (const float*)d_in[5];
  const float* b_ally  = (const float*)d_in[6];
  const float* W_cat   = (const float*)d_in[7];
  const float* b_cat   = (const float*)d_in[8];
  const float* W_ih    = (const float*)d_in[9];
  const float* W_hh    = (const float*)d_in[10];
  const float* b_ih    = (const float*)d_in[11];
  const float* b_hh    = (const float*)d_in[12];
  const float* W_pfc   = (const float*)d_in[13];
  const float* b_pfc   = (const float*)d_in[14];
  const float* W_vfc   = (const float*)d_in[15];
  const float* b_vfc   = (const float*)d_in[16];
  const float* W_mu    = (const float*)d_in[17];
  const float* b_mu    = (const float*)d_in[18];
  const float* W_ls    = (const float*)d_in[19];
  const float* b_ls    = (const float*)d_in[20];
  const float* W_v     = (const float*)d_in[21];
  const float* b_v     = (const float*)d_in[22];
  const float* h0      = (const float*)d_in[23];
  const float* c0      = (const float*)d_in[24];
  float* out = (float*)d_out;

  // workspace layout (bytes): start[8193] | avg[T*20] | xg[T*80] | hbuf[T*20]
  char* ws = (char*)d_ws;
  int*   start = (int*)(ws);
  float* avg   = (float*)(ws + 36864);
  float* xg    = (float*)(ws + 692224);
  float* hbuf  = (float*)(ws + 3313664);   // total ~3.97 MB

  // output layout: mu[T*16] | log_std_out[T*16] | v[T] | log_std[T*16]
  float* mu_out  = out;
  float* lso_out = out + 131072;
  float* v_out   = out + 262144;
  float* ls_out  = out + 270336;

  k_bounds<<<(T_STEPS + 256) / 256, 256, 0, stream>>>(seg, start);
  k_segmean<<<T_STEPS, 64, 0, stream>>>(ally_in, start, W_ally, b_ally, avg);
  k_feats<<<T_STEPS / 256, 256, 0, stream>>>(self_in, avg, W_self, b_self,
                                             W_cat, b_cat, W_ih, b_ih, b_hh,
                                             W_vfc, b_vfc, W_v, b_v, xg, v_out);
  k_lstm<<<1, 64, 0, stream>>>(xg, W_hh, h0, c0, hbuf);
  k_heads<<<T_STEPS / 256, 256, 0, stream>>>(hbuf, W_pfc, b_pfc, W_mu, b_mu,
                                             W_ls, b_ls, mu_out, lso_out, ls_out);
}

// Round 9
// 1570.139 us; speedup vs baseline: 1.9315x; 1.0530x over previous
//
#include <hip/hip_runtime.h>
#include <hip/hip_bf16.h>

// ---------------------------------------------------------------------------
// Model: self/ally tanh-Linear encoders -> segment mean -> cat MLP ->
//        8192-step LSTM (H=20) -> policy/value heads.
//   k_segmean : 1 wave/segment; FUSED segment-bounds binary search; coalesced
//               64-row LDS tiles; W via scalar loads
//   k_feats   : 64 blocks x 128 thr; xg float4, pre-scaled by log2e / 2*log2e
//   k_lstm    : single wave; i|f lanes 0-19|32-51 pass1, g|o pass2; dots via
//               v_pk_fma_f32 with h as SGPR pairs; MERGED gate rcp:
//               R=rcp((1+e1)(1+e2)); prod,f,op2 from R by lane-const fmas;
//               scaled cell cs=2*log2e*c; 8x unroll + 8-deep xg prefetch.
//   k_heads   : 64 blocks x 128 thr, float4 loads/stores
// ---------------------------------------------------------------------------

#define T_STEPS 8192
#define TOTAL_ROWS 1048576
#define DSELF 128
#define DALLY 64
#define HS 20
#define NOUT 16
#define L2E 1.44269504088896340736f

typedef float v2f __attribute__((ext_vector_type(2)));

__device__ __forceinline__ float rcp_f(float x) { return __builtin_amdgcn_rcpf(x); }
__device__ __forceinline__ float sigm_f(float x) { return rcp_f(1.0f + __expf(-x)); }
// tanh(x) = 2*sigmoid(2x) - 1 ; saturates correctly at +-inf
__device__ __forceinline__ float tanh_f(float x) { return fmaf(2.0f, sigm_f(2.0f * x), -1.0f); }

// packed fp32 FMA: acc.{lo,hi} += w.{lo,hi} * h.{lo,hi}; h is an SGPR pair.
__device__ __forceinline__ v2f pk_fma(v2f acc, v2f w, v2f h) {
  asm("v_pk_fma_f32 %0, %1, %2, %0" : "+v"(acc) : "v"(w), "s"(h));
  return acc;
}
__device__ __forceinline__ v2f pk_add(v2f a, v2f b) {
  v2f d;
  asm("v_pk_add_f32 %0, %1, %2" : "=v"(d) : "v"(a), "v"(b));
  return d;
}

// ------------------- K2: fused bounds + ally tanh-linear + segment mean -----
// one wave per segment. Segment bounds via two wave-uniform binary searches
// (seg sorted, every segment nonempty). Rows staged through LDS 64-row tiles.
__global__ __launch_bounds__(64) void k_segmean(
    const float* __restrict__ ally, const int* __restrict__ seg,
    const float* __restrict__ W_ally, const float* __restrict__ b_ally,
    float* __restrict__ avg) {
  __shared__ float tile[64][DALLY + 2];
  __shared__ float red[64][HS + 1];
  const int lane = threadIdx.x;
  const int s = blockIdx.x;
  // wave-uniform binary searches: r0 = lower_bound(seg, s), r1 = lower_bound(seg, s+1)
  int r0;
  {
    int lo = 0, hi = TOTAL_ROWS;
    while (lo < hi) { int mid = (lo + hi) >> 1; if (seg[mid] < s) lo = mid + 1; else hi = mid; }
    r0 = lo;
  }
  int r1;
  if (s == T_STEPS - 1) {
    r1 = TOTAL_ROWS;
  } else {
    int lo = r0, hi = TOTAL_ROWS;
    const int sp = s + 1;
    while (lo < hi) { int mid = (lo + hi) >> 1; if (seg[mid] < sp) lo = mid + 1; else hi = mid; }
    r1 = lo;
  }
  float acc[HS];
#pragma unroll
  for (int h = 0; h < HS; ++h) acc[h] = 0.0f;
  for (int base = r0; base < r1; base += 64) {
    const int m = min(64, r1 - base);
    __syncthreads();  // protect tile from previous iteration's readers
    for (int idx = lane; idx < m * 16; idx += 64) {
      const int rr = idx >> 4, cc = (idx & 15) << 2;
      const float4 v = *reinterpret_cast<const float4*>(
          ally + (size_t)(base + rr) * DALLY + cc);
      *reinterpret_cast<float2*>(&tile[rr][cc])     = make_float2(v.x, v.y);
      *reinterpret_cast<float2*>(&tile[rr][cc + 2]) = make_float2(v.z, v.w);
    }
    __syncthreads();
    if (lane < m) {
      float dot[HS];
#pragma unroll
      for (int h = 0; h < HS; ++h) dot[h] = b_ally[h];  // uniform -> SGPR
#pragma unroll
      for (int j = 0; j < DALLY; j += 4) {
        const float2 xa = *reinterpret_cast<const float2*>(&tile[lane][j]);
        const float2 xb = *reinterpret_cast<const float2*>(&tile[lane][j + 2]);
#pragma unroll
        for (int h = 0; h < HS; ++h) {
          const float4 w = *reinterpret_cast<const float4*>(&W_ally[h * DALLY + j]);
          dot[h] = fmaf(xa.x, w.x, dot[h]);
          dot[h] = fmaf(xa.y, w.y, dot[h]);
          dot[h] = fmaf(xb.x, w.z, dot[h]);
          dot[h] = fmaf(xb.y, w.w, dot[h]);
        }
      }
#pragma unroll
      for (int h = 0; h < HS; ++h) acc[h] += tanh_f(dot[h]);
    }
  }
#pragma unroll
  for (int h = 0; h < HS; ++h) red[lane][h] = acc[h];
  __syncthreads();
  if (lane < HS) {
    float t = 0.0f;
    for (int l = 0; l < 64; ++l) t += red[l][lane];
    avg[(size_t)s * HS + lane] = t / (float)(r1 - r0);
  }
}

// ------------- K3: per-timestep features: s, cat, xg(scaled), value ---------
__global__ __launch_bounds__(128) void k_feats(
    const float* __restrict__ self_in, const float* __restrict__ avg,
    const float* __restrict__ W_self, const float* __restrict__ b_self,
    const float* __restrict__ W_cat, const float* __restrict__ b_cat,
    const float* __restrict__ W_ih, const float* __restrict__ b_ih,
    const float* __restrict__ b_hh,
    const float* __restrict__ W_vfc, const float* __restrict__ b_vfc,
    const float* __restrict__ W_v, const float* __restrict__ b_v,
    float* __restrict__ xg, float* __restrict__ v_out) {
  __shared__ float s_ws[HS * DSELF];
  __shared__ float s_bs[HS];
  __shared__ float s_wc[HS * 2 * HS];
  __shared__ float s_bc[HS];
  __shared__ float s_wih[4 * HS * HS];
  __shared__ float s_bih[4 * HS];
  __shared__ float s_wv[HS * HS];
  __shared__ float s_bv[HS];
  __shared__ float s_wvv[HS];
  __shared__ float s_bvs;
  const int tid = threadIdx.x;
  for (int i = tid; i < HS * DSELF; i += 128) s_ws[i] = W_self[i];
  for (int i = tid; i < HS * 2 * HS; i += 128) s_wc[i] = W_cat[i];
  // exp2-folding: g rows ([800,1200)) scaled by 2*L2E, others by L2E.
  for (int i = tid; i < 4 * HS * HS; i += 128) {
    const float sc = (i >= 800 && i < 1200) ? (2.0f * L2E) : L2E;
    s_wih[i] = W_ih[i] * sc;
  }
  for (int i = tid; i < HS * HS; i += 128) s_wv[i] = W_vfc[i];
  if (tid < HS) {
    s_bs[tid] = b_self[tid]; s_bc[tid] = b_cat[tid];
    s_bv[tid] = b_vfc[tid];  s_wvv[tid] = W_v[tid];
  }
  if (tid < 4 * HS) {
    const float sc = (tid >= 40 && tid < 60) ? (2.0f * L2E) : L2E;
    s_bih[tid] = (b_ih[tid] + b_hh[tid]) * sc;
  }
  if (tid == 0) s_bvs = b_v[0];
  __syncthreads();

  const int t = blockIdx.x * 128 + tid;
  const float* srow = self_in + (size_t)t * DSELF;
  float acc[HS];
#pragma unroll
  for (int h = 0; h < HS; ++h) acc[h] = s_bs[h];
  for (int j = 0; j < DSELF / 4; ++j) {
    const float4 x = *reinterpret_cast<const float4*>(srow + j * 4);
#pragma unroll
    for (int h = 0; h < HS; ++h) {
      const float4 w = *reinterpret_cast<const float4*>(&s_ws[h * DSELF + j * 4]);
      acc[h] = fmaf(x.x, w.x, acc[h]);
      acc[h] = fmaf(x.y, w.y, acc[h]);
      acc[h] = fmaf(x.z, w.z, acc[h]);
      acc[h] = fmaf(x.w, w.w, acc[h]);
    }
  }
  float sv[HS], av[HS];
#pragma unroll
  for (int h = 0; h < HS; ++h) sv[h] = tanh_f(acc[h]);
  {
    const float4* ap = reinterpret_cast<const float4*>(avg + (size_t)t * HS);
#pragma unroll
    for (int q = 0; q < HS / 4; ++q) {
      const float4 a4 = ap[q];
      av[q * 4 + 0] = a4.x; av[q * 4 + 1] = a4.y;
      av[q * 4 + 2] = a4.z; av[q * 4 + 3] = a4.w;
    }
  }
  float cat[HS];
#pragma unroll
  for (int h = 0; h < HS; ++h) {
    float a = s_bc[h];
#pragma unroll
    for (int j = 0; j < HS; ++j) a = fmaf(sv[j], s_wc[h * 2 * HS + j], a);
#pragma unroll
    for (int j = 0; j < HS; ++j) a = fmaf(av[j], s_wc[h * 2 * HS + HS + j], a);
    cat[h] = tanh_f(a);
  }
  // xg written as float4 groups of gate rows (scaled pre-activations)
#pragma unroll 2
  for (int jj = 0; jj < 4 * HS; jj += 4) {
    float a0 = s_bih[jj], a1 = s_bih[jj + 1], a2 = s_bih[jj + 2], a3 = s_bih[jj + 3];
#pragma unroll
    for (int k = 0; k < HS; ++k) {
      const float cv = cat[k];
      a0 = fmaf(cv, s_wih[(jj + 0) * HS + k], a0);
      a1 = fmaf(cv, s_wih[(jj + 1) * HS + k], a1);
      a2 = fmaf(cv, s_wih[(jj + 2) * HS + k], a2);
      a3 = fmaf(cv, s_wih[(jj + 3) * HS + k], a3);
    }
    float4 o4; o4.x = a0; o4.y = a1; o4.z = a2; o4.w = a3;
    *reinterpret_cast<float4*>(&xg[(size_t)t * 80 + jj]) = o4;
  }
  float vacc = s_bvs;
#pragma unroll
  for (int h = 0; h < HS; ++h) {
    float a = s_bv[h];
#pragma unroll
    for (int k = 0; k < HS; ++k) a = fmaf(cat[k], s_wv[h * HS + k], a);
    vacc = fmaf(tanh_f(a), s_wvv[h], vacc);
  }
  v_out[t] = vacc;
}

// ----------------------------- K4: LSTM scan --------------------------------
// Single wave, exp2-folded, scaled cell, MERGED GATE RCP:
//   e1=2^-a1, e2=2^-a2, D=(1+e1)(1+e2), R=rcp(D)
//   lanes 0-19:  P1 = n*R = [2L2E(1-e2)]*R = i * (2L2E*tanh(g))   (prod)
//   lanes 32-51: P1 = n*R = (1+e2)*R = f ;  P2 = m*R = 2(1+e1)*R = 2o
//   (n via lane-const fma; m = fma(2,e1,2) uniform)
// f, 2o cross to lanes 0-19 via permlane32_swap. cs' = f*cs + prod.
// hn = o*tanh(c) = fma(op2, uc, -0.5*op2), ho=-0.5*op2 computed under the
// cell-exp shadow. 8x unroll, 8-deep xg prefetch (tail reads spill <=2560B
// into hbuf region: valid memory, values never consumed).
#define LSTM_STEP(X1, X2, K)                                                  \
  do {                                                                        \
    v2f pA = {(X1), 0.0f}, pB = {0.0f, 0.0f};                                 \
    v2f qA = {(X2), 0.0f}, qB = {0.0f, 0.0f};                                 \
    _Pragma("unroll") for (int j = 0; j < 10; j += 2) {                       \
      const v2f h2a = {hs[2 * j],     hs[2 * j + 1]};                         \
      const v2f h2b = {hs[2 * j + 2], hs[2 * j + 3]};                         \
      pA = pk_fma(pA, wa2[j],     h2a);                                       \
      qA = pk_fma(qA, wb2[j],     h2a);                                       \
      pB = pk_fma(pB, wa2[j + 1], h2b);                                       \
      qB = pk_fma(qB, wb2[j + 1], h2b);                                       \
    }                                                                         \
    pA = pk_add(pA, pB);                                                      \
    qA = pk_add(qA, qB);                                                      \
    const float a1 = pA.x + pA.y;                                             \
    const float a2 = qA.x + qA.y;                                             \
    (X1) = px1[(K + 8) * 80];                                                 \
    (X2) = px2[(K + 8) * 80];                                                 \
    const float e1 = __builtin_amdgcn_exp2f(-a1);                             \
    const float e2 = __builtin_amdgcn_exp2f(-a2);                             \
    const float d1 = 1.0f + e1;                                               \
    const float d2 = 1.0f + e2;                                               \
    const float R  = rcp_f(d1 * d2);                                          \
    const float n  = fmaf(Bn, e2, An);   /* 2L2E(1-e2) | (1+e2) */            \
    const float m  = fmaf(2.0f, e1, 2.0f); /* - | 2(1+e1) */                  \
    const float P1 = n * R;              /* prod | f */                       \
    const float P2 = m * R;              /* -    | 2o */                      \
    auto rfp = __builtin_amdgcn_permlane32_swap(                              \
        __float_as_uint(P1), __float_as_uint(P1), false, false);              \
    auto rop = __builtin_amdgcn_permlane32_swap(                              \
        __float_as_uint(P2), __float_as_uint(P2), false, false);              \
    const float fp  = __uint_as_float(rfp[1]);   /* lane k: f_k */            \
    const float op2 = __uint_as_float(rop[1]);   /* lane k: 2*o_k */          \
    cs = fmaf(fp, cs, P1);                       /* scaled cell */            \
    const float ho = -0.5f * op2;                /* off-path */               \
    const float ec = __builtin_amdgcn_exp2f(-cs);                             \
    const float uc = rcp_f(1.0f + ec);           /* sig(2c) */                \
    const float hn = fmaf(op2, uc, ho);          /* o * tanh(c) */            \
    if (lane < HS) hp[(K)*HS] = hn;                                           \
    const unsigned hu = __float_as_uint(hn);                                  \
    _Pragma("unroll") for (int j = 0; j < HS; ++j)                            \
        hs[j] = __uint_as_float(__builtin_amdgcn_readlane(hu, j));            \
  } while (0)

__global__ __launch_bounds__(64) void k_lstm(
    const float* __restrict__ xg, const float* __restrict__ Whh,
    const float* __restrict__ h0, const float* __restrict__ c0,
    float* __restrict__ hout) {
  const int lane = threadIdx.x;
  const int kk = lane & 31;
  const int kc = kk < HS ? kk : HS - 1;            // clamp dup lanes
  const int r1 = kc + ((lane >= 32) ? HS : 0);     // i rows | f rows
  const int r2 = r1 + 2 * HS;                      // g rows | o rows

  // merged-rcp lane constants: n = fma(Bn, e2, An)
  const float An = (lane < 32) ? 2.0f * L2E : 1.0f;
  const float Bn = (lane < 32) ? -2.0f * L2E : 1.0f;
  // W_hh row scales: pass1 (i,f) -> L2E; pass2 g -> 2L2E, o -> L2E
  const float s2v = (lane < 32) ? 2.0f * L2E : L2E;

  v2f wa2[10], wb2[10];
  {
    const v2f* ra = reinterpret_cast<const v2f*>(Whh + (size_t)r1 * HS);
    const v2f* rb = reinterpret_cast<const v2f*>(Whh + (size_t)r2 * HS);
#pragma unroll
    for (int j = 0; j < 10; ++j) {
      v2f a = ra[j], b = rb[j];
      a.x *= L2E; a.y *= L2E;
      b.x *= s2v; b.y *= s2v;
      wa2[j] = a; wb2[j] = b;
    }
  }

  float hs[HS];
#pragma unroll
  for (int j = 0; j < HS; ++j) hs[j] = h0[j];      // uniform -> s_load
  float cs = c0[kc] * (2.0f * L2E);                // scaled cell

  const float* px1 = xg + r1;
  const float* px2 = xg + r2;
  float x10 = px1[0 * 80], x20 = px2[0 * 80];
  float x11 = px1[1 * 80], x21 = px2[1 * 80];
  float x12 = px1[2 * 80], x22 = px2[2 * 80];
  float x13 = px1[3 * 80], x23 = px2[3 * 80];
  float x14 = px1[4 * 80], x24 = px2[4 * 80];
  float x15 = px1[5 * 80], x25 = px2[5 * 80];
  float x16 = px1[6 * 80], x26 = px2[6 * 80];
  float x17 = px1[7 * 80], x27 = px2[7 * 80];
  float* hp = hout + lane;

  for (int t = 0; t < T_STEPS; t += 8) {
    LSTM_STEP(x10, x20, 0);
    LSTM_STEP(x11, x21, 1);
    LSTM_STEP(x12, x22, 2);
    LSTM_STEP(x13, x23, 3);
    LSTM_STEP(x14, x24, 4);
    LSTM_STEP(x15, x25, 5);
    LSTM_STEP(x16, x26, 6);
    LSTM_STEP(x17, x27, 7);
    px1 += 8 * 80; px2 += 8 * 80; hp += 8 * HS;
  }
}

// ----------------------------- K5: output heads ------------------------------
__global__ __launch_bounds__(128) void k_heads(
    const float* __restrict__ hbuf,
    const float* __restrict__ W_pfc, const float* __restrict__ b_pfc,
    const float* __restrict__ W_mu, const float* __restrict__ b_mu,
    const float* __restrict__ W_ls, const float* __restrict__ b_ls,
    float* __restrict__ mu_out, float* __restrict__ lso_out,
    float* __restrict__ ls_out) {
  __shared__ float wp[HS * HS], bp[HS], wm[NOUT * HS], bm[NOUT], wl[NOUT * HS], bl[NOUT];
  const int tid = threadIdx.x;
  for (int i = tid; i < HS * HS; i += 128) wp[i] = W_pfc[i];
  for (int i = tid; i < NOUT * HS; i += 128) { wm[i] = W_mu[i]; wl[i] = W_ls[i]; }
  if (tid < HS) bp[tid] = b_pfc[tid];
  if (tid < NOUT) { bm[tid] = b_mu[tid]; bl[tid] = b_ls[tid]; }
  __syncthreads();
  const int t = blockIdx.x * 128 + tid;
  float hr[HS];
  {
    const float4* hp4 = reinterpret_cast<const float4*>(hbuf + (size_t)t * HS);
#pragma unroll
    for (int q = 0; q < HS / 4; ++q) {
      const float4 h4 = hp4[q];
      hr[q * 4 + 0] = h4.x; hr[q * 4 + 1] = h4.y;
      hr[q * 4 + 2] = h4.z; hr[q * 4 + 3] = h4.w;
    }
  }
  float x[HS];
#pragma unroll
  for (int h = 0; h < HS; ++h) {
    float a = bp[h];
#pragma unroll
    for (int k = 0; k < HS; ++k) a = fmaf(hr[k], wp[h * HS + k], a);
    x[h] = tanh_f(a);
  }
  float4* mo4 = reinterpret_cast<float4*>(mu_out + (size_t)t * NOUT);
  float4* lo4 = reinterpret_cast<float4*>(lso_out + (size_t)t * NOUT);
  float4* lb4 = reinterpret_cast<float4*>(ls_out + (size_t)t * NOUT);
#pragma unroll
  for (int m = 0; m < NOUT; m += 4) {
    float4 mu4, lsb4, lso4;
    float am[4], bm_[4];
#pragma unroll
    for (int q = 0; q < 4; ++q) { am[q] = bm[m + q]; bm_[q] = bl[m + q]; }
#pragma unroll
    for (int k = 0; k < HS; ++k) {
      const float xv = x[k];
#pragma unroll
      for (int q = 0; q < 4; ++q) {
        am[q]  = fmaf(xv, wm[(m + q) * HS + k], am[q]);
        bm_[q] = fmaf(xv, wl[(m + q) * HS + k], bm_[q]);
      }
    }
    mu4.x = tanh_f(am[0]); mu4.y = tanh_f(am[1]);
    mu4.z = tanh_f(am[2]); mu4.w = tanh_f(am[3]);
    lsb4.x = bm_[0]; lsb4.y = bm_[1]; lsb4.z = bm_[2]; lsb4.w = bm_[3];
    lso4.x = __expf(fmaxf(bm_[0], 0.0f) - 2.0f);
    lso4.y = __expf(fmaxf(bm_[1], 0.0f) - 2.0f);
    lso4.z = __expf(fmaxf(bm_[2], 0.0f) - 2.0f);
    lso4.w = __expf(fmaxf(bm_[3], 0.0f) - 2.0f);
    mo4[m / 4] = mu4; lb4[m / 4] = lsb4; lo4[m / 4] = lso4;
  }
}

// ---------------------------------------------------------------------------
extern "C" void kernel_launch(void* const* d_in, const int* in_sizes, int n_in,
                              void* d_out, int out_size, void* d_ws, size_t ws_size,
                              hipStream_t stream) {
  const float* self_in = (const float*)d_in[0];
  const float* ally_in = (const float*)d_in[1];
  const int*   seg     = (const int*)d_in[2];
  const float* W_self  = (const float*)d_in[3];
  const float* b_self  = (const float*)d_in[4];
  const float* W_ally  = (const float*)d_in[5];
  const float* b_ally  = (const float*)d_in[6];
  const float* W_cat   = (const float*)d_in[7];
  const float* b_cat   = (const float*)d_in[8];
  const float* W_ih    = (const float*)d_in[9];
  const float* W_hh    = (const float*)d_in[10];
  const float* b_ih    = (const float*)d_in[11];
  const float* b_hh    = (const float*)d_in[12];
  const float* W_pfc   = (const float*)d_in[13];
  const float* b_pfc   = (const float*)d_in[14];
  const float* W_vfc   = (const float*)d_in[15];
  const float* b_vfc   = (const float*)d_in[16];
  const float* W_mu    = (const float*)d_in[17];
  const float* b_mu    = (const float*)d_in[18];
  const float* W_ls    = (const float*)d_in[19];
  const float* b_ls    = (const float*)d_in[20];
  const float* W_v     = (const float*)d_in[21];
  const float* b_v     = (const float*)d_in[22];
  const float* h0      = (const float*)d_in[23];
  const float* c0      = (const float*)d_in[24];
  float* out = (float*)d_out;

  // workspace layout (bytes): avg[T*20] @36864 | xg[T*80] | hbuf[T*20]
  char* ws = (char*)d_ws;
  float* avg   = (float*)(ws + 36864);
  float* xg    = (float*)(ws + 692224);
  float* hbuf  = (float*)(ws + 3313664);   // total ~3.97 MB

  // output layout: mu[T*16] | log_std_out[T*16] | v[T] | log_std[T*16]
  float* mu_out  = out;
  float* lso_out = out + 131072;
  float* v_out   = out + 262144;
  float* ls_out  = out + 270336;

  k_segmean<<<T_STEPS, 64, 0, stream>>>(ally_in, seg, W_ally, b_ally, avg);
  k_feats<<<T_STEPS / 128, 128, 0, stream>>>(self_in, avg, W_self, b_self,
                                             W_cat, b_cat, W_ih, b_ih, b_hh,
                                             W_vfc, b_vfc, W_v, b_v, xg, v_out);
  k_lstm<<<1, 64, 0, stream>>>(xg, W_hh, h0, c0, hbuf);
  k_heads<<<T_STEPS / 128, 128, 0, stream>>>(hbuf, W_pfc, b_pfc, W_mu, b_mu,
                                             W_ls, b_ls, mu_out, lso_out, ls_out);
}